// Round 12
// baseline (956.451 us; speedup 1.0000x reference)
//
#include <hip/hip_runtime.h>

#define DI __device__ __forceinline__

typedef short s16x8 __attribute__((ext_vector_type(8)));
typedef float f32x4 __attribute__((ext_vector_type(4)));

typedef __attribute__((address_space(1))) const unsigned int as1_cuint;
typedef __attribute__((address_space(3))) unsigned int as3_uint;

DI unsigned short f2bf(float f) {
  union { float f; unsigned int u; } v; v.f = f;
  unsigned int r = v.u + 0x7fffu + ((v.u >> 16) & 1u);
  return (unsigned short)(r >> 16);
}
DI float bf2f(unsigned short b) {
  union { unsigned int u; float f; } v; v.u = ((unsigned int)b) << 16;
  return v.f;
}

DI void gl_lds16(const void* g, void* l) {
  __builtin_amdgcn_global_load_lds((as1_cuint*)g, (as3_uint*)l, 16, 0, 0);
}

DI void bar() {
  __builtin_amdgcn_sched_barrier(0);
  __builtin_amdgcn_s_barrier();
  __builtin_amdgcn_sched_barrier(0);
}
DI void vm0() { asm volatile("s_waitcnt vmcnt(0)" ::: "memory"); }
DI void sfence() { __builtin_amdgcn_sched_barrier(0); }

#define MFMA __builtin_amdgcn_mfma_f32_16x16x32_bf16

DI ushort4 cvt4f(float4 v) {
  return make_ushort4(f2bf(v.x), f2bf(v.y), f2bf(v.z), f2bf(v.w));
}

// ---------- batched convert: Wq,Wk,Wv -> wqkv (contiguous), Wo -> wo ----------
__global__ __launch_bounds__(256) void cvt_qkvo(const float* __restrict__ Wq,
                                               const float* __restrict__ Wk,
                                               const float* __restrict__ Wv,
                                               const float* __restrict__ Wo,
                                               unsigned short* __restrict__ wqkv,
                                               unsigned short* __restrict__ wo) {
  const int SEG = 1 << 20;  // 1M float4 per matrix (2048*2048/4)
  int stride = gridDim.x * blockDim.x;
  for (int i = blockIdx.x * blockDim.x + threadIdx.x; i < 4 * SEG; i += stride) {
    int seg = i >> 20, within = i & (SEG - 1);
    const float4* src = (const float4*)(seg == 0 ? Wq : seg == 1 ? Wk : seg == 2 ? Wv : Wo);
    float4 v = src[within];
    if (seg < 3) ((ushort4*)wqkv)[i] = cvt4f(v);
    else ((ushort4*)wo)[within] = cvt4f(v);
  }
}

// ---------- batched convert: Win -> win, Wup -> wup ----------
__global__ __launch_bounds__(256) void cvt_gu(const float* __restrict__ Win,
                                              const float* __restrict__ Wup,
                                              unsigned short* __restrict__ win,
                                              unsigned short* __restrict__ wup) {
  const int SEG = 1 << 22;  // 4M float4 per matrix (8192*2048/4)
  int stride = gridDim.x * blockDim.x;
  for (int i = blockIdx.x * blockDim.x + threadIdx.x; i < 2 * SEG; i += stride) {
    int seg = i >> 22, within = i & (SEG - 1);
    float4 v = ((const float4*)(seg ? Wup : Win))[within];
    ((ushort4*)(seg ? wup : win))[within] = cvt4f(v);
  }
}

// ---------------- fp32 -> bf16 convert (single matrix) ----------------
__global__ __launch_bounds__(256) void cvt_f32_bf16(const float* __restrict__ src,
                                                    unsigned short* __restrict__ dst, int n4) {
  int i = blockIdx.x * blockDim.x + threadIdx.x;
  int stride = gridDim.x * blockDim.x;
  for (; i < n4; i += stride) ((ushort4*)dst)[i] = cvt4f(((const float4*)src)[i]);
}

// ---------------- dual RMSNorm ----------------
__global__ __launch_bounds__(256) void rmsnorm_dual(const float* __restrict__ hs,
                                                    const float* __restrict__ w1,
                                                    const float* __restrict__ w2,
                                                    unsigned short* __restrict__ xo,
                                                    unsigned short* __restrict__ ho) {
  const int D = 2048;
  int t = blockIdx.x, tid = threadIdx.x;
  const float* row = hs + (size_t)t * D;
  float4 a = ((const float4*)row)[tid * 2];
  float4 b = ((const float4*)row)[tid * 2 + 1];
  float ss = a.x * a.x + a.y * a.y + a.z * a.z + a.w * a.w +
             b.x * b.x + b.y * b.y + b.z * b.z + b.w * b.w;
#pragma unroll
  for (int off = 32; off; off >>= 1) ss += __shfl_xor(ss, off);
  __shared__ float red[4];
  int wave = tid >> 6, lane = tid & 63;
  if (lane == 0) red[wave] = ss;
  __syncthreads();
  float tot = red[0] + red[1] + red[2] + red[3];
  float inv = rsqrtf(tot / (float)D + 1e-6f);
  int base = tid * 8;
  float vals[8] = {a.x, a.y, a.z, a.w, b.x, b.y, b.z, b.w};
  float4 w1a = ((const float4*)(w1 + base))[0];
  float4 w1b = ((const float4*)(w1 + base))[1];
  float4 w2a = ((const float4*)(w2 + base))[0];
  float4 w2b = ((const float4*)(w2 + base))[1];
  float w1v[8] = {w1a.x, w1a.y, w1a.z, w1a.w, w1b.x, w1b.y, w1b.z, w1b.w};
  float w2v[8] = {w2a.x, w2a.y, w2a.z, w2a.w, w2b.x, w2b.y, w2b.z, w2b.w};
  unsigned short ox[8], oh[8];
#pragma unroll
  for (int j = 0; j < 8; ++j) {
    float n = vals[j] * inv;
    ox[j] = f2bf(n * w1v[j]);
    oh[j] = f2bf(n * w2v[j]);
  }
  ushort4* xp = (ushort4*)(xo + (size_t)t * D + base);
  ushort4* hp = (ushort4*)(ho + (size_t)t * D + base);
  xp[0] = make_ushort4(ox[0], ox[1], ox[2], ox[3]);
  xp[1] = make_ushort4(ox[4], ox[5], ox[6], ox[7]);
  hp[0] = make_ushort4(oh[0], oh[1], oh[2], oh[3]);
  hp[1] = make_ushort4(oh[4], oh[5], oh[6], oh[7]);
}

// ======== 256x128 1-barrier/K-tile GEMM (774-us artifact): C = A @ Bt^T ========
#define E_NONE 0
#define E_RES 3

template <int EPI>
__global__ __launch_bounds__(512, 2) void gemm_n128(
    const unsigned short* __restrict__ Amat, const unsigned short* __restrict__ Bt,
    int N, int K, int NT,
    unsigned short* __restrict__ Cbf, float* __restrict__ Cf,
    const float* __restrict__ Res) {
  __shared__ __align__(16) unsigned short lds[49152];
  int tid = threadIdx.x, lane = tid & 63;
  int w = tid >> 6, wm = w >> 2, wn = w & 3;
  int lr = lane & 15, g = lane >> 4;
  int nbn = N >> 7, nwg = gridDim.x, wg = blockIdx.x;
  int cpx = nwg >> 3;
  int swz = (wg & 7) * cpx + (wg >> 3);
  int tm = swz / nbn, tn = swz - tm * nbn;
  size_t m0 = (size_t)tm * 256, n0 = (size_t)tn * 128;

  int boffA[4][2], boffB[2][2];
#pragma unroll
  for (int mi = 0; mi < 4; ++mi)
#pragma unroll
    for (int kh = 0; kh < 2; ++kh) {
      int row = mi * 32 + wm * 16 + lr;
      boffA[mi][kh] = row * 128 + ((kh * 64 + g * 16) ^ ((row & 7) << 4));
    }
#pragma unroll
  for (int ni = 0; ni < 2; ++ni)
#pragma unroll
    for (int kh = 0; kh < 2; ++kh) {
      int row = ni * 64 + wn * 16 + lr;
      boffB[ni][kh] = row * 128 + ((kh * 64 + g * 16) ^ ((row & 7) << 4));
    }
  const char* ldsb = (const char*)lds;

  int srow = tid >> 3;
  int scb = ((tid & 7) * 16) ^ ((srow & 7) << 4);
  const unsigned short* pA0 = Amat + (m0 + srow) * (size_t)K + (scb >> 1);
  const unsigned short* pA1 = pA0 + (size_t)128 * K;
  const unsigned short* pB  = Bt + (n0 + srow) * (size_t)K + (scb >> 1);
  const size_t jst = (size_t)64 * K;
  int dst = w * 512;

  f32x4 acc[8][2] = {};

  auto stg = [&](const unsigned short* p, int SLOT) {
    gl_lds16(p, &lds[SLOT * 8192 + dst]);
    gl_lds16(p + jst, &lds[SLOT * 8192 + 4096 + dst]);
  };
  auto stg_all = [&]() {
    stg(pA0, 0); stg(pA1, 1); stg(pB, 2);
    pA0 += 64; pA1 += 64; pB += 64;
  };

  for (int t = 0; t < NT; ++t) {
    bar();
    stg_all();
    vm0();
    bar();
    s16x8 afr[4][2], bfr[2][2];
#pragma unroll
    for (int mi = 0; mi < 4; ++mi)
#pragma unroll
      for (int kh = 0; kh < 2; ++kh)
        afr[mi][kh] = *(const s16x8*)(ldsb + 0 * 16384 + boffA[mi][kh]);
#pragma unroll
    for (int ni = 0; ni < 2; ++ni)
#pragma unroll
      for (int kh = 0; kh < 2; ++kh)
        bfr[ni][kh] = *(const s16x8*)(ldsb + 2 * 16384 + boffB[ni][kh]);
    __builtin_amdgcn_s_setprio(1);
#pragma unroll
    for (int mi = 0; mi < 4; ++mi)
#pragma unroll
      for (int ni = 0; ni < 2; ++ni)
#pragma unroll
        for (int kh = 0; kh < 2; ++kh)
          acc[mi][ni] = MFMA(afr[mi][kh], bfr[ni][kh], acc[mi][ni], 0, 0, 0);
    __builtin_amdgcn_s_setprio(0);
    s16x8 af1[4][2];
#pragma unroll
    for (int mi = 0; mi < 4; ++mi)
#pragma unroll
      for (int kh = 0; kh < 2; ++kh)
        af1[mi][kh] = *(const s16x8*)(ldsb + 1 * 16384 + boffA[mi][kh]);
    __builtin_amdgcn_s_setprio(1);
#pragma unroll
    for (int mi = 0; mi < 4; ++mi)
#pragma unroll
      for (int ni = 0; ni < 2; ++ni)
#pragma unroll
        for (int kh = 0; kh < 2; ++kh)
          acc[4 + mi][ni] = MFMA(af1[mi][kh], bfr[ni][kh], acc[4 + mi][ni], 0, 0, 0);
    __builtin_amdgcn_s_setprio(0);
  }

#pragma unroll
  for (int mh = 0; mh < 2; ++mh)
#pragma unroll
    for (int mi = 0; mi < 4; ++mi)
#pragma unroll
      for (int r = 0; r < 4; ++r) {
        size_t row = m0 + mh * 128 + mi * 32 + wm * 16 + g * 4 + r;
#pragma unroll
        for (int ni = 0; ni < 2; ++ni) {
          size_t col = n0 + ni * 64 + wn * 16 + lr;
          float v = acc[mh * 4 + mi][ni][r];
          if constexpr (EPI == E_RES) Cf[row * N + col] = Res[row * N + col] + v;
          else Cbf[row * N + col] = f2bf(v);
        }
      }
}

// ===== 256x128 1-barrier/K-tile fused MLP (774-us artifact) =====
__global__ __launch_bounds__(512, 2) void gemm_mlp256(
    const unsigned short* __restrict__ Hm, const unsigned short* __restrict__ Wg,
    const unsigned short* __restrict__ Wu,
    const float* __restrict__ cvec, const float* __restrict__ Bsm,
    unsigned short* __restrict__ Out) {
  const int N = 8192, K = 2048, NT = 32;
  __shared__ __align__(16) unsigned short lds[65536];
  int tid = threadIdx.x, lane = tid & 63;
  int w = tid >> 6, wm = w >> 2, wn = w & 3;
  int lr = lane & 15, g = lane >> 4;
  int nbn = N >> 7, nwg = gridDim.x, wg = blockIdx.x;
  int cpx = nwg >> 3;
  int swz = (wg & 7) * cpx + (wg >> 3);
  int tm = swz / nbn, tn = swz - tm * nbn;
  size_t m0 = (size_t)tm * 256, n0 = (size_t)tn * 128;

  int boffA[4][2], boffB[2][2];
#pragma unroll
  for (int mi = 0; mi < 4; ++mi)
#pragma unroll
    for (int kh = 0; kh < 2; ++kh) {
      int row = mi * 32 + wm * 16 + lr;
      boffA[mi][kh] = row * 128 + ((kh * 64 + g * 16) ^ ((row & 7) << 4));
    }
#pragma unroll
  for (int ni = 0; ni < 2; ++ni)
#pragma unroll
    for (int kh = 0; kh < 2; ++kh) {
      int row = ni * 64 + wn * 16 + lr;
      boffB[ni][kh] = row * 128 + ((kh * 64 + g * 16) ^ ((row & 7) << 4));
    }
  const char* ldsb = (const char*)lds;

  int srow = tid >> 3;
  int scb = ((tid & 7) * 16) ^ ((srow & 7) << 4);
  const unsigned short* pA0 = Hm + (m0 + srow) * (size_t)K + (scb >> 1);
  const unsigned short* pA1 = pA0 + (size_t)128 * K;
  const unsigned short* pBg = Wg + (n0 + srow) * (size_t)K + (scb >> 1);
  const unsigned short* pBu = Wu + (n0 + srow) * (size_t)K + (scb >> 1);
  const size_t jst = (size_t)64 * K;
  int dst = w * 512;

  f32x4 ag[8][2] = {}, au[8][2] = {};

  auto stg = [&](const unsigned short* p, int SLOT) {
    gl_lds16(p, &lds[SLOT * 8192 + dst]);
    gl_lds16(p + jst, &lds[SLOT * 8192 + 4096 + dst]);
  };
  auto stg_all = [&]() {
    stg(pA0, 0); stg(pA1, 1); stg(pBg, 2); stg(pBu, 3);
    pA0 += 64; pA1 += 64; pBg += 64; pBu += 64;
  };

  for (int t = 0; t < NT; ++t) {
    bar();
    stg_all();
    vm0();
    bar();
    s16x8 afr[4][2], bg[2][2], bu[2][2];
#pragma unroll
    for (int mi = 0; mi < 4; ++mi)
#pragma unroll
      for (int kh = 0; kh < 2; ++kh)
        afr[mi][kh] = *(const s16x8*)(ldsb + 0 * 16384 + boffA[mi][kh]);
#pragma unroll
    for (int ni = 0; ni < 2; ++ni)
#pragma unroll
      for (int kh = 0; kh < 2; ++kh) {
        bg[ni][kh] = *(const s16x8*)(ldsb + 2 * 16384 + boffB[ni][kh]);
        bu[ni][kh] = *(const s16x8*)(ldsb + 3 * 16384 + boffB[ni][kh]);
      }
    __builtin_amdgcn_s_setprio(1);
#pragma unroll
    for (int mi = 0; mi < 4; ++mi)
#pragma unroll
      for (int ni = 0; ni < 2; ++ni)
#pragma unroll
        for (int kh = 0; kh < 2; ++kh) {
          ag[mi][ni] = MFMA(afr[mi][kh], bg[ni][kh], ag[mi][ni], 0, 0, 0);
          au[mi][ni] = MFMA(afr[mi][kh], bu[ni][kh], au[mi][ni], 0, 0, 0);
        }
    __builtin_amdgcn_s_setprio(0);
    s16x8 af1[4][2];
#pragma unroll
    for (int mi = 0; mi < 4; ++mi)
#pragma unroll
      for (int kh = 0; kh < 2; ++kh)
        af1[mi][kh] = *(const s16x8*)(ldsb + 1 * 16384 + boffA[mi][kh]);
    __builtin_amdgcn_s_setprio(1);
#pragma unroll
    for (int mi = 0; mi < 4; ++mi)
#pragma unroll
      for (int ni = 0; ni < 2; ++ni)
#pragma unroll
        for (int kh = 0; kh < 2; ++kh) {
          ag[4 + mi][ni] = MFMA(af1[mi][kh], bg[ni][kh], ag[4 + mi][ni], 0, 0, 0);
          au[4 + mi][ni] = MFMA(af1[mi][kh], bu[ni][kh], au[4 + mi][ni], 0, 0, 0);
        }
    __builtin_amdgcn_s_setprio(0);
  }

  // epilogue: c-tile 256x16 f32 + Bsm-tile 16x128 f32 into reused LDS
  bar();
  float* cl = (float*)lds;          // [256][16]
  float* bl = (float*)&lds[32768];  // [16][128]
#pragma unroll
  for (int j = 0; j < 2; ++j) {
    int fi = tid * 2 + j;
    ((float4*)cl)[fi] = ((const float4*)(cvec + m0 * 16))[fi];
  }
  {
    int fi = tid;
    ((float4*)bl)[fi] = *(const float4*)(Bsm + (size_t)(fi >> 5) * N + n0 + (fi & 31) * 4);
  }
  bar();

#pragma unroll
  for (int mh = 0; mh < 2; ++mh)
#pragma unroll
    for (int mi = 0; mi < 4; ++mi)
#pragma unroll
      for (int r = 0; r < 4; ++r) {
        int rr = mh * 128 + mi * 32 + wm * 16 + g * 4 + r;
        size_t row = m0 + rr;
#pragma unroll
        for (int ni = 0; ni < 2; ++ni) {
          int cc = ni * 64 + wn * 16 + lr;
          size_t col = n0 + cc;
          float s = 0.f;
#pragma unroll
          for (int jj = 0; jj < 16; ++jj) s += cl[rr * 16 + jj] * bl[jj * 128 + cc];
          float gg = ag[mh * 4 + mi][ni][r] + s;
          float sig = 1.f / (1.f + __expf(-gg));
          Out[row * N + col] = f2bf(gg * sig * au[mh * 4 + mi][ni][r]);
        }
      }
}

// ---------- V transpose: vT[bh][d][k] ----------
__global__ __launch_bounds__(256) void vtrans(const unsigned short* __restrict__ qkv,
                                              unsigned short* __restrict__ vT) {
  __shared__ unsigned short t[64][72];
  int bh = blockIdx.z, b = bh >> 4, h = bh & 15;
  int k0 = blockIdx.x * 64, d0 = blockIdx.y * 64;
  int tid = threadIdx.x;
#pragma unroll
  for (int j = 0; j < 2; ++j) {
    int idx = tid + j * 256;
    int r = idx >> 3, c8 = (idx & 7) * 8;
    s16x8 v = *(const s16x8*)(qkv + ((size_t)(b * 2048 + k0 + r)) * 6144 + 4096 + h * 128 + d0 + c8);
#pragma unroll
    for (int e = 0; e < 8; ++e) t[r][c8 + e] = (unsigned short)v[e];
  }
  __syncthreads();
#pragma unroll
  for (int j = 0; j < 2; ++j) {
    int idx = tid + j * 256;
    int dr = idx >> 3, k8 = (idx & 7) * 8;
    s16x8 o;
#pragma unroll
    for (int e = 0; e < 8; ++e) o[e] = (short)t[k8 + e][dr];
    *(s16x8*)(vT + (size_t)bh * 262144 + (size_t)(d0 + dr) * 2048 + k0 + k8) = o;
  }
}

// ---------- causal flash attention v3: KVBLK=64, double-staged k-tile pairs ----------
// LDS 72KB (2 blocks/CU): Kt[2][8192], Vt[2][8192], Pl[4096].
// Per 2 k-tiles: one {bar, stage both, vm0, bar} then two compute rounds back-to-back.
__global__ __launch_bounds__(256, 2) void attn_fwd3(const unsigned short* __restrict__ qkv,
                                                    const unsigned short* __restrict__ vT,
                                                    unsigned short* __restrict__ attn) {
  const int LD = 6144;
  __shared__ __align__(16) unsigned short Kt[16384];
  __shared__ __align__(16) unsigned short Vt[16384];
  __shared__ __align__(16) unsigned short Pl[4096];
  int tid = threadIdx.x, w = tid >> 6, lane = tid & 63;
  int lrow = lane & 15, g = lane >> 4;
  int qp = blockIdx.x, bh = blockIdx.y, b = bh >> 4, h = bh & 15;
  const unsigned short* Qb = qkv + (size_t)b * 2048 * LD + h * 128;
  const unsigned short* Kb = Qb + 2048;
  const unsigned short* vTb = vT + (size_t)bh * 262144;
  const float scale = 0.08838834764831845f;

#pragma unroll
  for (int pass = 0; pass < 2; ++pass) {
    int qtile = pass ? (31 - qp) : qp;
    int wq0 = qtile * 64 + w * 16;
    s16x8 qf[4];
#pragma unroll
    for (int kc = 0; kc < 4; ++kc)
      qf[kc] = *(const s16x8*)(Qb + (size_t)(wq0 + lrow) * LD + kc * 32 + g * 8);
    f32x4 ao[8] = {};
    float m_r[4], l_r[4];
#pragma unroll
    for (int r = 0; r < 4; ++r) { m_r[r] = -1e30f; l_r[r] = 0.f; }
    int nkt = qtile + 1;

    for (int kt = 0; kt < nkt; kt += 2) {
      bar();  // all waves done reading previous pair
      // stage k-tile kt -> buf0, kt+1 -> buf1 (if present)
#pragma unroll
      for (int bu = 0; bu < 2; ++bu) {
        int ktt = kt + bu;
        if (ktt >= nkt) break;
        int k0 = ktt * 64;
#pragma unroll
        for (int j = 0; j < 4; ++j) {
          int o = j * 4096 + tid * 16;
          int row = o >> 8, cb = o & 255;
          int scb = cb ^ ((row & 7) << 4);
          gl_lds16(Kb + (size_t)(k0 + row) * LD + (scb >> 1),
                   &Kt[bu * 8192 + ((j * 4096 + w * 1024) >> 1)]);
        }
#pragma unroll
        for (int j = 0; j < 4; ++j) {
          int o = j * 4096 + tid * 16;
          int row = o >> 7, cb = o & 127;
          int scb = cb ^ ((row & 7) << 4);
          gl_lds16(vTb + (size_t)row * 2048 + k0 + (scb >> 1),
                   &Vt[bu * 8192 + ((j * 4096 + w * 1024) >> 1)]);
        }
      }
      vm0();
      bar();
      // two compute rounds (no barrier between: disjoint LDS buffers, Pl is per-wave)
#pragma unroll
      for (int bu = 0; bu < 2; ++bu) {
        int ktt = kt + bu;
        if (ktt >= nkt) break;
        int k0 = ktt * 64;
        int kb = bu * 8192;
        f32x4 sa[4] = {};
#pragma unroll
        for (int ni = 0; ni < 4; ++ni)
#pragma unroll
          for (int kc = 0; kc < 4; ++kc) {
            int row = ni * 16 + lrow;
            int cb = kc * 64 + g * 16;
            int scb = cb ^ ((row & 7) << 4);
            s16x8 kf = *(const s16x8*)&Kt[kb + row * 128 + (scb >> 1)];
            sa[ni] = MFMA(qf[kc], kf, sa[ni], 0, 0, 0);
          }
        if (k0 + 63 > wq0) {
#pragma unroll
          for (int ni = 0; ni < 4; ++ni)
#pragma unroll
            for (int r = 0; r < 4; ++r) {
              int q_idx = wq0 + g * 4 + r, k_idx = k0 + ni * 16 + lrow;
              float sv = sa[ni][r] * scale;
              sa[ni][r] = (k_idx > q_idx) ? -1e30f : sv;
            }
        } else {
#pragma unroll
          for (int ni = 0; ni < 4; ++ni)
#pragma unroll
            for (int r = 0; r < 4; ++r) sa[ni][r] *= scale;
        }
        float mt[4];
#pragma unroll
        for (int r = 0; r < 4; ++r)
          mt[r] = fmaxf(fmaxf(sa[0][r], sa[1][r]), fmaxf(sa[2][r], sa[3][r]));
#pragma unroll
        for (int r = 0; r < 4; ++r)
#pragma unroll
          for (int off = 8; off; off >>= 1) mt[r] = fmaxf(mt[r], __shfl_xor(mt[r], off));
        float al[4];
#pragma unroll
        for (int r = 0; r < 4; ++r) {
          float mn = fmaxf(m_r[r], mt[r]);
          al[r] = __expf(m_r[r] - mn);
          m_r[r] = mn;
        }
        float rs[4] = {0.f, 0.f, 0.f, 0.f};
#pragma unroll
        for (int ni = 0; ni < 4; ++ni)
#pragma unroll
          for (int r = 0; r < 4; ++r) {
            float p = __expf(sa[ni][r] - m_r[r]);
            rs[r] += p;
            int q = g * 4 + r, k = ni * 16 + lrow;
            Pl[w * 1024 + q * 64 + (k ^ ((q & 7) << 3))] = f2bf(p);
          }
#pragma unroll
        for (int r = 0; r < 4; ++r) {
#pragma unroll
          for (int off = 8; off; off >>= 1) rs[r] += __shfl_xor(rs[r], off);
          l_r[r] = l_r[r] * al[r] + rs[r];
        }
#pragma unroll
        for (int df = 0; df < 8; ++df)
#pragma unroll
          for (int r = 0; r < 4; ++r) ao[df][r] *= al[r];
        asm volatile("s_waitcnt lgkmcnt(0)" ::: "memory");
        __builtin_amdgcn_sched_barrier(0);
        s16x8 pa[2];
#pragma unroll
        for (int ks = 0; ks < 2; ++ks)
          pa[ks] = *(const s16x8*)&Pl[w * 1024 + lrow * 64 + ((ks * 32 + g * 8) ^ ((lrow & 7) << 3))];
#pragma unroll
        for (int df = 0; df < 8; ++df) {
#pragma unroll
          for (int ks = 0; ks < 2; ++ks) {
            int row = df * 16 + lrow;
            int cb = ks * 64 + g * 16;
            int scb = cb ^ ((row & 7) << 4);
            s16x8 vf = *(const s16x8*)&Vt[kb + row * 64 + (scb >> 1)];
            ao[df] = MFMA(pa[ks], vf, ao[df], 0, 0, 0);
          }
        }
      }
    }
#pragma unroll
    for (int df = 0; df < 8; ++df)
#pragma unroll
      for (int r = 0; r < 4; ++r) {
        int q = wq0 + g * 4 + r;
        float v = ao[df][r] / l_r[r];
        attn[((size_t)b * 2048 + q) * 2048 + h * 128 + df * 16 + lrow] = f2bf(v);
      }
    bar();
  }
}

// ---------------- modc ----------------
__global__ __launch_bounds__(256) void modc(const unsigned short* __restrict__ attnO,
                                            const unsigned short* __restrict__ h,
                                            const float* __restrict__ A,
                                            float* __restrict__ cvec) {
  const int D = 2048;
  int t = blockIdx.x * 4 + (threadIdx.x >> 6);
  int lane = threadIdx.x & 63;
  float aA[16] = {}, aH[16] = {};
  for (int i = 0; i < D / 64; ++i) {
    int d = i * 64 + lane;
    float av = bf2f(attnO[(size_t)t * D + d]);
    float hv = bf2f(h[(size_t)t * D + d]);
    const float* ar = A + (size_t)d * 16;
#pragma unroll
    for (int j = 0; j < 16; ++j) {
      float a = ar[j];
      aA[j] += av * a;
      aH[j] += hv * a;
    }
  }
#pragma unroll
  for (int j = 0; j < 16; ++j) {
#pragma unroll
    for (int off = 32; off; off >>= 1) {
      aA[j] += __shfl_xor(aA[j], off);
      aH[j] += __shfl_xor(aH[j], off);
    }
  }
#pragma unroll
  for (int j = 0; j < 16; ++j)
    if (lane == j) cvec[(size_t)t * 16 + j] = 0.1f * tanhf(aA[j]) * aH[j];
}

extern "C" void kernel_launch(void* const* d_in, const int* in_sizes, int n_in,
                              void* d_out, int out_size, void* d_ws, size_t ws_size,
                              hipStream_t stream) {
  const float* hs  = (const float*)d_in[0];
  const float* ln1 = (const float*)d_in[1];
  const float* ln2 = (const float*)d_in[2];
  const float* Wq  = (const float*)d_in[3];
  const float* Wk  = (const float*)d_in[4];
  const float* Wv  = (const float*)d_in[5];
  const float* Wo  = (const float*)d_in[6];
  const float* Am  = (const float*)d_in[7];
  const float* Bm  = (const float*)d_in[8];
  const float* Win = (const float*)d_in[9];
  const float* Wup = (const float*)d_in[10];
  const float* Wdn = (const float*)d_in[11];
  float* out = (float*)d_out;
  (void)in_sizes; (void)n_in;

  const int T = 4096;
  const int Dm = 2048, F = 8192;
  const size_t MB = (size_t)1 << 20;

  const size_t need = 184 * MB;
  if (ws_size < need) {
    hipMemsetAsync(d_out, 0, (size_t)out_size * 4, stream);
    return;
  }
  char* base = (char*)d_ws;
  unsigned short* tb    = (unsigned short*)(base);
  unsigned short* wqkv  = (unsigned short*)(base);
  unsigned short* vT    = (unsigned short*)(base);
  unsigned short* xb    = (unsigned short*)(base + 24 * MB);
  unsigned short* attnO = (unsigned short*)(base + 40 * MB);
  unsigned short* qkv   = (unsigned short*)(base + 64 * MB);
  unsigned short* win   = (unsigned short*)(base + 64 * MB);
  unsigned short* wo    = (unsigned short*)(base + 112 * MB);
  unsigned short* hb    = (unsigned short*)(base + 120 * MB);
  unsigned short* attn  = (unsigned short*)(base + 136 * MB);
  float*          cv    = (float*)(base + 136 * MB);
  unsigned short* wup   = (unsigned short*)(base + 152 * MB);
  unsigned short* wdn   = (unsigned short*)(base + 152 * MB);

  // batched QKV/O weight convert (1 launch instead of 4)
  cvt_qkvo<<<2048, 256, 0, stream>>>(Wq, Wk, Wv, Wo, wqkv, wo);
  rmsnorm_dual<<<T, 256, 0, stream>>>(hs, ln1, ln2, xb, hb);

  // QKV projection: 16 x 48 = 768 blocks (3 exact rounds)
  gemm_n128<E_NONE><<<(T / 256) * (3 * Dm / 128), 512, 0, stream>>>(
      xb, wqkv, 3 * Dm, Dm, Dm / 64, qkv, nullptr, nullptr);

  vtrans<<<dim3(32, 2, 32), 256, 0, stream>>>(qkv, vT);
  attn_fwd3<<<dim3(16, 32), 256, 0, stream>>>(qkv, vT, attn);

  // MLP weight converts (qkv region now dead) — 1 launch instead of 2
  cvt_gu<<<2048, 256, 0, stream>>>(Win, Wup, win, wup);

  // O projection: 16 x 16 = 256 blocks (1 exact round)
  gemm_n128<E_NONE><<<(T / 256) * (Dm / 128), 512, 0, stream>>>(
      attn, wo, Dm, Dm, Dm / 64, attnO, nullptr, nullptr);

  modc<<<T / 4, 256, 0, stream>>>(attnO, hb, Am, cv);

  // fused gate/up: 16 x 64 = 1024 blocks (4 exact rounds)
  gemm_mlp256<<<(T / 256) * (F / 128), 512, 0, stream>>>(hb, win, wup, cv, Bm, tb);

  cvt_f32_bf16<<<2048, 256, 0, stream>>>(Wdn, wdn, Dm * F / 4);
  // down + residual: 16 x 16 = 256 blocks (1 exact round), K=8192
  gemm_n128<E_RES><<<(T / 256) * (Dm / 128), 512, 0, stream>>>(
      tb, wdn, Dm, F, F / 64, nullptr, out, hs);
}

// Round 13
// 767.753 us; speedup vs baseline: 1.2458x; 1.2458x over previous
//
#include <hip/hip_runtime.h>

#define DI __device__ __forceinline__

typedef short s16x8 __attribute__((ext_vector_type(8)));
typedef float f32x4 __attribute__((ext_vector_type(4)));

typedef __attribute__((address_space(1))) const unsigned int as1_cuint;
typedef __attribute__((address_space(3))) unsigned int as3_uint;

DI unsigned short f2bf(float f) {
  union { float f; unsigned int u; } v; v.f = f;
  unsigned int r = v.u + 0x7fffu + ((v.u >> 16) & 1u);
  return (unsigned short)(r >> 16);
}
DI float bf2f(unsigned short b) {
  union { unsigned int u; float f; } v; v.u = ((unsigned int)b) << 16;
  return v.f;
}

DI void gl_lds16(const void* g, void* l) {
  __builtin_amdgcn_global_load_lds((as1_cuint*)g, (as3_uint*)l, 16, 0, 0);
}

DI void bar() {
  __builtin_amdgcn_sched_barrier(0);
  __builtin_amdgcn_s_barrier();
  __builtin_amdgcn_sched_barrier(0);
}
DI void vm0() { asm volatile("s_waitcnt vmcnt(0)" ::: "memory"); }
DI void sfence() { __builtin_amdgcn_sched_barrier(0); }

#define MFMA __builtin_amdgcn_mfma_f32_16x16x32_bf16

DI ushort4 cvt4f(float4 v) {
  return make_ushort4(f2bf(v.x), f2bf(v.y), f2bf(v.z), f2bf(v.w));
}

// ---------- batched convert: Wq,Wk,Wv -> wqkv (contiguous), Wo -> wo ----------
__global__ __launch_bounds__(256) void cvt_qkvo(const float* __restrict__ Wq,
                                               const float* __restrict__ Wk,
                                               const float* __restrict__ Wv,
                                               const float* __restrict__ Wo,
                                               unsigned short* __restrict__ wqkv,
                                               unsigned short* __restrict__ wo) {
  const int SEG = 1 << 20;  // 1M float4 per matrix
  int stride = gridDim.x * blockDim.x;
  for (int i = blockIdx.x * blockDim.x + threadIdx.x; i < 4 * SEG; i += stride) {
    int seg = i >> 20, within = i & (SEG - 1);
    const float4* src = (const float4*)(seg == 0 ? Wq : seg == 1 ? Wk : seg == 2 ? Wv : Wo);
    float4 v = src[within];
    if (seg < 3) ((ushort4*)wqkv)[i] = cvt4f(v);
    else ((ushort4*)wo)[within] = cvt4f(v);
  }
}

// ---------- batched convert: Win -> win, Wup -> wup ----------
__global__ __launch_bounds__(256) void cvt_gu(const float* __restrict__ Win,
                                              const float* __restrict__ Wup,
                                              unsigned short* __restrict__ win,
                                              unsigned short* __restrict__ wup) {
  const int SEG = 1 << 22;  // 4M float4 per matrix
  int stride = gridDim.x * blockDim.x;
  for (int i = blockIdx.x * blockDim.x + threadIdx.x; i < 2 * SEG; i += stride) {
    int seg = i >> 22, within = i & (SEG - 1);
    float4 v = ((const float4*)(seg ? Wup : Win))[within];
    ((ushort4*)(seg ? wup : win))[within] = cvt4f(v);
  }
}

// ---------------- fp32 -> bf16 convert (single matrix) ----------------
__global__ __launch_bounds__(256) void cvt_f32_bf16(const float* __restrict__ src,
                                                    unsigned short* __restrict__ dst, int n4) {
  int i = blockIdx.x * blockDim.x + threadIdx.x;
  int stride = gridDim.x * blockDim.x;
  for (; i < n4; i += stride) ((ushort4*)dst)[i] = cvt4f(((const float4*)src)[i]);
}

// ---------------- dual RMSNorm ----------------
__global__ __launch_bounds__(256) void rmsnorm_dual(const float* __restrict__ hs,
                                                    const float* __restrict__ w1,
                                                    const float* __restrict__ w2,
                                                    unsigned short* __restrict__ xo,
                                                    unsigned short* __restrict__ ho) {
  const int D = 2048;
  int t = blockIdx.x, tid = threadIdx.x;
  const float* row = hs + (size_t)t * D;
  float4 a = ((const float4*)row)[tid * 2];
  float4 b = ((const float4*)row)[tid * 2 + 1];
  float ss = a.x * a.x + a.y * a.y + a.z * a.z + a.w * a.w +
             b.x * b.x + b.y * b.y + b.z * b.z + b.w * b.w;
#pragma unroll
  for (int off = 32; off; off >>= 1) ss += __shfl_xor(ss, off);
  __shared__ float red[4];
  int wave = tid >> 6, lane = tid & 63;
  if (lane == 0) red[wave] = ss;
  __syncthreads();
  float tot = red[0] + red[1] + red[2] + red[3];
  float inv = rsqrtf(tot / (float)D + 1e-6f);
  int base = tid * 8;
  float vals[8] = {a.x, a.y, a.z, a.w, b.x, b.y, b.z, b.w};
  float4 w1a = ((const float4*)(w1 + base))[0];
  float4 w1b = ((const float4*)(w1 + base))[1];
  float4 w2a = ((const float4*)(w2 + base))[0];
  float4 w2b = ((const float4*)(w2 + base))[1];
  float w1v[8] = {w1a.x, w1a.y, w1a.z, w1a.w, w1b.x, w1b.y, w1b.z, w1b.w};
  float w2v[8] = {w2a.x, w2a.y, w2a.z, w2a.w, w2b.x, w2b.y, w2b.z, w2b.w};
  unsigned short ox[8], oh[8];
#pragma unroll
  for (int j = 0; j < 8; ++j) {
    float n = vals[j] * inv;
    ox[j] = f2bf(n * w1v[j]);
    oh[j] = f2bf(n * w2v[j]);
  }
  ushort4* xp = (ushort4*)(xo + (size_t)t * D + base);
  ushort4* hp = (ushort4*)(ho + (size_t)t * D + base);
  xp[0] = make_ushort4(ox[0], ox[1], ox[2], ox[3]);
  xp[1] = make_ushort4(ox[4], ox[5], ox[6], ox[7]);
  hp[0] = make_ushort4(oh[0], oh[1], oh[2], oh[3]);
  hp[1] = make_ushort4(oh[4], oh[5], oh[6], oh[7]);
}

// ======== 256x128 1-barrier/K-tile GEMM (774-us artifact, double-buffered prefetch) ========
// Tile t: [reads A0+B from buf t][stage ALL of t+1 into buf^1][sfence][16 MFMA]
//         [reads A1][16 MFMA][vm0 (full-tile slack)][bar]
#define E_NONE 0
#define E_RES 3

template <int EPI>
__global__ __launch_bounds__(512, 2) void gemm_n128(
    const unsigned short* __restrict__ Amat, const unsigned short* __restrict__ Bt,
    int N, int K, int NT,
    unsigned short* __restrict__ Cbf, float* __restrict__ Cf,
    const float* __restrict__ Res) {
  __shared__ __align__(16) unsigned short lds[49152];
  int tid = threadIdx.x, lane = tid & 63;
  int w = tid >> 6, wm = w >> 2, wn = w & 3;
  int lr = lane & 15, g = lane >> 4;
  int nbn = N >> 7, nwg = gridDim.x, wg = blockIdx.x;
  int cpx = nwg >> 3;
  int swz = (wg & 7) * cpx + (wg >> 3);
  int tm = swz / nbn, tn = swz - tm * nbn;
  size_t m0 = (size_t)tm * 256, n0 = (size_t)tn * 128;

  int boffA[4][2], boffB[2][2];
#pragma unroll
  for (int mi = 0; mi < 4; ++mi)
#pragma unroll
    for (int kh = 0; kh < 2; ++kh) {
      int row = mi * 32 + wm * 16 + lr;
      boffA[mi][kh] = row * 128 + ((kh * 64 + g * 16) ^ ((row & 7) << 4));
    }
#pragma unroll
  for (int ni = 0; ni < 2; ++ni)
#pragma unroll
    for (int kh = 0; kh < 2; ++kh) {
      int row = ni * 64 + wn * 16 + lr;
      boffB[ni][kh] = row * 128 + ((kh * 64 + g * 16) ^ ((row & 7) << 4));
    }
  const char* ldsb = (const char*)lds;

  int srow = tid >> 3;
  int scb = ((tid & 7) * 16) ^ ((srow & 7) << 4);
  const unsigned short* pA0 = Amat + (m0 + srow) * (size_t)K + (scb >> 1);
  const unsigned short* pA1 = pA0 + (size_t)128 * K;
  const unsigned short* pB  = Bt + (n0 + srow) * (size_t)K + (scb >> 1);
  const size_t jst = (size_t)64 * K;
  int dst = w * 512;

  f32x4 acc[8][2] = {};

  auto stg = [&](const unsigned short* p, int BUF, int SLOT) {
    gl_lds16(p, &lds[BUF * 24576 + SLOT * 8192 + dst]);
    gl_lds16(p + jst, &lds[BUF * 24576 + SLOT * 8192 + 4096 + dst]);
  };
  auto stg_all = [&](int BUF) {
    stg(pA0, BUF, 0); stg(pA1, BUF, 1); stg(pB, BUF, 2);
    pA0 += 64; pA1 += 64; pB += 64;
  };

  stg_all(0);
  vm0();
  bar();

  for (int t = 0; t < NT; ++t) {
    int BUF = t & 1;
    s16x8 afr[4][2], bfr[2][2];
#pragma unroll
    for (int mi = 0; mi < 4; ++mi)
#pragma unroll
      for (int kh = 0; kh < 2; ++kh)
        afr[mi][kh] = *(const s16x8*)(ldsb + BUF * 49152 + 0 * 16384 + boffA[mi][kh]);
#pragma unroll
    for (int ni = 0; ni < 2; ++ni)
#pragma unroll
      for (int kh = 0; kh < 2; ++kh)
        bfr[ni][kh] = *(const s16x8*)(ldsb + BUF * 49152 + 2 * 16384 + boffB[ni][kh]);
    if (t + 1 < NT) stg_all(BUF ^ 1);
    sfence();  // pin stage issue before MFMA cluster
    __builtin_amdgcn_s_setprio(1);
#pragma unroll
    for (int mi = 0; mi < 4; ++mi)
#pragma unroll
      for (int ni = 0; ni < 2; ++ni)
#pragma unroll
        for (int kh = 0; kh < 2; ++kh)
          acc[mi][ni] = MFMA(afr[mi][kh], bfr[ni][kh], acc[mi][ni], 0, 0, 0);
    __builtin_amdgcn_s_setprio(0);
    s16x8 af1[4][2];
#pragma unroll
    for (int mi = 0; mi < 4; ++mi)
#pragma unroll
      for (int kh = 0; kh < 2; ++kh)
        af1[mi][kh] = *(const s16x8*)(ldsb + BUF * 49152 + 1 * 16384 + boffA[mi][kh]);
    __builtin_amdgcn_s_setprio(1);
#pragma unroll
    for (int mi = 0; mi < 4; ++mi)
#pragma unroll
      for (int ni = 0; ni < 2; ++ni)
#pragma unroll
        for (int kh = 0; kh < 2; ++kh)
          acc[4 + mi][ni] = MFMA(af1[mi][kh], bfr[ni][kh], acc[4 + mi][ni], 0, 0, 0);
    __builtin_amdgcn_s_setprio(0);
    vm0();
    bar();
  }

#pragma unroll
  for (int mh = 0; mh < 2; ++mh)
#pragma unroll
    for (int mi = 0; mi < 4; ++mi)
#pragma unroll
      for (int r = 0; r < 4; ++r) {
        size_t row = m0 + mh * 128 + mi * 32 + wm * 16 + g * 4 + r;
#pragma unroll
        for (int ni = 0; ni < 2; ++ni) {
          size_t col = n0 + ni * 64 + wn * 16 + lr;
          float v = acc[mh * 4 + mi][ni][r];
          if constexpr (EPI == E_RES) Cf[row * N + col] = Res[row * N + col] + v;
          else Cbf[row * N + col] = f2bf(v);
        }
      }
}

// ===== 256x128 1-barrier/K-tile fused MLP (774-us artifact, double-buffered prefetch) =====
__global__ __launch_bounds__(512, 2) void gemm_mlp256(
    const unsigned short* __restrict__ Hm, const unsigned short* __restrict__ Wg,
    const unsigned short* __restrict__ Wu,
    const float* __restrict__ cvec, const float* __restrict__ Bsm,
    unsigned short* __restrict__ Out) {
  const int N = 8192, K = 2048, NT = 32;
  __shared__ __align__(16) unsigned short lds[65536];
  int tid = threadIdx.x, lane = tid & 63;
  int w = tid >> 6, wm = w >> 2, wn = w & 3;
  int lr = lane & 15, g = lane >> 4;
  int nbn = N >> 7, nwg = gridDim.x, wg = blockIdx.x;
  int cpx = nwg >> 3;
  int swz = (wg & 7) * cpx + (wg >> 3);
  int tm = swz / nbn, tn = swz - tm * nbn;
  size_t m0 = (size_t)tm * 256, n0 = (size_t)tn * 128;

  int boffA[4][2], boffB[2][2];
#pragma unroll
  for (int mi = 0; mi < 4; ++mi)
#pragma unroll
    for (int kh = 0; kh < 2; ++kh) {
      int row = mi * 32 + wm * 16 + lr;
      boffA[mi][kh] = row * 128 + ((kh * 64 + g * 16) ^ ((row & 7) << 4));
    }
#pragma unroll
  for (int ni = 0; ni < 2; ++ni)
#pragma unroll
    for (int kh = 0; kh < 2; ++kh) {
      int row = ni * 64 + wn * 16 + lr;
      boffB[ni][kh] = row * 128 + ((kh * 64 + g * 16) ^ ((row & 7) << 4));
    }
  const char* ldsb = (const char*)lds;

  int srow = tid >> 3;
  int scb = ((tid & 7) * 16) ^ ((srow & 7) << 4);
  const unsigned short* pA0 = Hm + (m0 + srow) * (size_t)K + (scb >> 1);
  const unsigned short* pA1 = pA0 + (size_t)128 * K;
  const unsigned short* pBg = Wg + (n0 + srow) * (size_t)K + (scb >> 1);
  const unsigned short* pBu = Wu + (n0 + srow) * (size_t)K + (scb >> 1);
  const size_t jst = (size_t)64 * K;
  int dst = w * 512;

  f32x4 ag[8][2] = {}, au[8][2] = {};

  auto stg = [&](const unsigned short* p, int BUF, int SLOT) {
    gl_lds16(p, &lds[BUF * 32768 + SLOT * 8192 + dst]);
    gl_lds16(p + jst, &lds[BUF * 32768 + SLOT * 8192 + 4096 + dst]);
  };
  auto stg_all = [&](int BUF) {
    stg(pA0, BUF, 0); stg(pA1, BUF, 1); stg(pBg, BUF, 2); stg(pBu, BUF, 3);
    pA0 += 64; pA1 += 64; pBg += 64; pBu += 64;
  };

  stg_all(0);
  vm0();
  bar();

  for (int t = 0; t < NT; ++t) {
    int BUF = t & 1;
    s16x8 afr[4][2], bg[2][2], bu[2][2];
#pragma unroll
    for (int mi = 0; mi < 4; ++mi)
#pragma unroll
      for (int kh = 0; kh < 2; ++kh)
        afr[mi][kh] = *(const s16x8*)(ldsb + BUF * 65536 + 0 * 16384 + boffA[mi][kh]);
#pragma unroll
    for (int ni = 0; ni < 2; ++ni)
#pragma unroll
      for (int kh = 0; kh < 2; ++kh) {
        bg[ni][kh] = *(const s16x8*)(ldsb + BUF * 65536 + 2 * 16384 + boffB[ni][kh]);
        bu[ni][kh] = *(const s16x8*)(ldsb + BUF * 65536 + 3 * 16384 + boffB[ni][kh]);
      }
    if (t + 1 < NT) stg_all(BUF ^ 1);
    sfence();  // pin stage issue before MFMA cluster
    __builtin_amdgcn_s_setprio(1);
#pragma unroll
    for (int mi = 0; mi < 4; ++mi)
#pragma unroll
      for (int ni = 0; ni < 2; ++ni)
#pragma unroll
        for (int kh = 0; kh < 2; ++kh) {
          ag[mi][ni] = MFMA(afr[mi][kh], bg[ni][kh], ag[mi][ni], 0, 0, 0);
          au[mi][ni] = MFMA(afr[mi][kh], bu[ni][kh], au[mi][ni], 0, 0, 0);
        }
    __builtin_amdgcn_s_setprio(0);
    s16x8 af1[4][2];
#pragma unroll
    for (int mi = 0; mi < 4; ++mi)
#pragma unroll
      for (int kh = 0; kh < 2; ++kh)
        af1[mi][kh] = *(const s16x8*)(ldsb + BUF * 65536 + 1 * 16384 + boffA[mi][kh]);
    __builtin_amdgcn_s_setprio(1);
#pragma unroll
    for (int mi = 0; mi < 4; ++mi)
#pragma unroll
      for (int ni = 0; ni < 2; ++ni)
#pragma unroll
        for (int kh = 0; kh < 2; ++kh) {
          ag[4 + mi][ni] = MFMA(af1[mi][kh], bg[ni][kh], ag[4 + mi][ni], 0, 0, 0);
          au[4 + mi][ni] = MFMA(af1[mi][kh], bu[ni][kh], au[4 + mi][ni], 0, 0, 0);
        }
    __builtin_amdgcn_s_setprio(0);
    vm0();
    bar();
  }

  // epilogue: c-tile 256x16 f32 + Bsm-tile 16x128 f32 into reused LDS
  float* cl = (float*)lds;          // [256][16]
  float* bl = (float*)&lds[32768];  // [16][128]
#pragma unroll
  for (int j = 0; j < 2; ++j) {
    int fi = tid * 2 + j;
    ((float4*)cl)[fi] = ((const float4*)(cvec + m0 * 16))[fi];
  }
  {
    int fi = tid;
    ((float4*)bl)[fi] = *(const float4*)(Bsm + (size_t)(fi >> 5) * N + n0 + (fi & 31) * 4);
  }
  bar();

#pragma unroll
  for (int mh = 0; mh < 2; ++mh)
#pragma unroll
    for (int mi = 0; mi < 4; ++mi)
#pragma unroll
      for (int r = 0; r < 4; ++r) {
        int rr = mh * 128 + mi * 32 + wm * 16 + g * 4 + r;
        size_t row = m0 + rr;
#pragma unroll
        for (int ni = 0; ni < 2; ++ni) {
          int cc = ni * 64 + wn * 16 + lr;
          size_t col = n0 + cc;
          float s = 0.f;
#pragma unroll
          for (int jj = 0; jj < 16; ++jj) s += cl[rr * 16 + jj] * bl[jj * 128 + cc];
          float gg = ag[mh * 4 + mi][ni][r] + s;
          float sig = 1.f / (1.f + __expf(-gg));
          Out[row * N + col] = f2bf(gg * sig * au[mh * 4 + mi][ni][r]);
        }
      }
}

// ---------- V transpose: vT[bh][d][k] ----------
__global__ __launch_bounds__(256) void vtrans(const unsigned short* __restrict__ qkv,
                                              unsigned short* __restrict__ vT) {
  __shared__ unsigned short t[64][72];
  int bh = blockIdx.z, b = bh >> 4, h = bh & 15;
  int k0 = blockIdx.x * 64, d0 = blockIdx.y * 64;
  int tid = threadIdx.x;
#pragma unroll
  for (int j = 0; j < 2; ++j) {
    int idx = tid + j * 256;
    int r = idx >> 3, c8 = (idx & 7) * 8;
    s16x8 v = *(const s16x8*)(qkv + ((size_t)(b * 2048 + k0 + r)) * 6144 + 4096 + h * 128 + d0 + c8);
#pragma unroll
    for (int e = 0; e < 8; ++e) t[r][c8 + e] = (unsigned short)v[e];
  }
  __syncthreads();
#pragma unroll
  for (int j = 0; j < 2; ++j) {
    int idx = tid + j * 256;
    int dr = idx >> 3, k8 = (idx & 7) * 8;
    s16x8 o;
#pragma unroll
    for (int e = 0; e < 8; ++e) o[e] = (short)t[k8 + e][dr];
    *(s16x8*)(vT + (size_t)bh * 262144 + (size_t)(d0 + dr) * 2048 + k0 + k8) = o;
  }
}

// ---------- causal flash attention: KVBLK=64, vT staging, balanced pair-pass ----------
__global__ __launch_bounds__(256, 2) void attn_fwd2(const unsigned short* __restrict__ qkv,
                                                    const unsigned short* __restrict__ vT,
                                                    unsigned short* __restrict__ attn) {
  const int LD = 6144;
  __shared__ __align__(16) unsigned short Kt[8192];
  __shared__ __align__(16) unsigned short Vt[8192];
  __shared__ __align__(16) unsigned short Pl[4096];
  int tid = threadIdx.x, w = tid >> 6, lane = tid & 63;
  int lrow = lane & 15, g = lane >> 4;
  int qp = blockIdx.x, bh = blockIdx.y, b = bh >> 4, h = bh & 15;
  const unsigned short* Qb = qkv + (size_t)b * 2048 * LD + h * 128;
  const unsigned short* Kb = Qb + 2048;
  const unsigned short* vTb = vT + (size_t)bh * 262144;
  const float scale = 0.08838834764831845f;

#pragma unroll
  for (int pass = 0; pass < 2; ++pass) {
    int qtile = pass ? (31 - qp) : qp;
    int wq0 = qtile * 64 + w * 16;
    s16x8 qf[4];
#pragma unroll
    for (int kc = 0; kc < 4; ++kc)
      qf[kc] = *(const s16x8*)(Qb + (size_t)(wq0 + lrow) * LD + kc * 32 + g * 8);
    f32x4 ao[8] = {};
    float m_r[4], l_r[4];
#pragma unroll
    for (int r = 0; r < 4; ++r) { m_r[r] = -1e30f; l_r[r] = 0.f; }
    int nkt = qtile + 1;

    for (int kt = 0; kt < nkt; ++kt) {
      int k0 = kt * 64;
      bar();
#pragma unroll
      for (int j = 0; j < 4; ++j) {
        int o = j * 4096 + tid * 16;
        int row = o >> 8, cb = o & 255;
        int scb = cb ^ ((row & 7) << 4);
        gl_lds16(Kb + (size_t)(k0 + row) * LD + (scb >> 1), &Kt[(j * 4096 + w * 1024) >> 1]);
      }
#pragma unroll
      for (int j = 0; j < 4; ++j) {
        int o = j * 4096 + tid * 16;
        int row = o >> 7, cb = o & 127;
        int scb = cb ^ ((row & 7) << 4);
        gl_lds16(vTb + (size_t)row * 2048 + k0 + (scb >> 1), &Vt[(j * 4096 + w * 1024) >> 1]);
      }
      vm0();
      bar();
      f32x4 sa[4] = {};
#pragma unroll
      for (int ni = 0; ni < 4; ++ni)
#pragma unroll
        for (int kc = 0; kc < 4; ++kc) {
          int row = ni * 16 + lrow;
          int cb = kc * 64 + g * 16;
          int scb = cb ^ ((row & 7) << 4);
          s16x8 kf = *(const s16x8*)&Kt[row * 128 + (scb >> 1)];
          sa[ni] = MFMA(qf[kc], kf, sa[ni], 0, 0, 0);
        }
      if (k0 + 63 > wq0) {
#pragma unroll
        for (int ni = 0; ni < 4; ++ni)
#pragma unroll
          for (int r = 0; r < 4; ++r) {
            int q_idx = wq0 + g * 4 + r, k_idx = k0 + ni * 16 + lrow;
            float sv = sa[ni][r] * scale;
            sa[ni][r] = (k_idx > q_idx) ? -1e30f : sv;
          }
      } else {
#pragma unroll
        for (int ni = 0; ni < 4; ++ni)
#pragma unroll
          for (int r = 0; r < 4; ++r) sa[ni][r] *= scale;
      }
      float mt[4];
#pragma unroll
      for (int r = 0; r < 4; ++r)
        mt[r] = fmaxf(fmaxf(sa[0][r], sa[1][r]), fmaxf(sa[2][r], sa[3][r]));
#pragma unroll
      for (int r = 0; r < 4; ++r)
#pragma unroll
        for (int off = 8; off; off >>= 1) mt[r] = fmaxf(mt[r], __shfl_xor(mt[r], off));
      float al[4];
#pragma unroll
      for (int r = 0; r < 4; ++r) {
        float mn = fmaxf(m_r[r], mt[r]);
        al[r] = __expf(m_r[r] - mn);
        m_r[r] = mn;
      }
      float rs[4] = {0.f, 0.f, 0.f, 0.f};
#pragma unroll
      for (int ni = 0; ni < 4; ++ni)
#pragma unroll
        for (int r = 0; r < 4; ++r) {
          float p = __expf(sa[ni][r] - m_r[r]);
          rs[r] += p;
          int q = g * 4 + r, k = ni * 16 + lrow;
          Pl[w * 1024 + q * 64 + (k ^ ((q & 7) << 3))] = f2bf(p);
        }
#pragma unroll
      for (int r = 0; r < 4; ++r) {
#pragma unroll
        for (int off = 8; off; off >>= 1) rs[r] += __shfl_xor(rs[r], off);
        l_r[r] = l_r[r] * al[r] + rs[r];
      }
#pragma unroll
      for (int df = 0; df < 8; ++df)
#pragma unroll
        for (int r = 0; r < 4; ++r) ao[df][r] *= al[r];
      asm volatile("s_waitcnt lgkmcnt(0)" ::: "memory");
      __builtin_amdgcn_sched_barrier(0);
      s16x8 pa[2];
#pragma unroll
      for (int ks = 0; ks < 2; ++ks)
        pa[ks] = *(const s16x8*)&Pl[w * 1024 + lrow * 64 + ((ks * 32 + g * 8) ^ ((lrow & 7) << 3))];
#pragma unroll
      for (int df = 0; df < 8; ++df) {
#pragma unroll
        for (int ks = 0; ks < 2; ++ks) {
          int row = df * 16 + lrow;
          int cb = ks * 64 + g * 16;
          int scb = cb ^ ((row & 7) << 4);
          s16x8 vf = *(const s16x8*)&Vt[row * 64 + (scb >> 1)];
          ao[df] = MFMA(pa[ks], vf, ao[df], 0, 0, 0);
        }
      }
    }
#pragma unroll
    for (int df = 0; df < 8; ++df)
#pragma unroll
      for (int r = 0; r < 4; ++r) {
        int q = wq0 + g * 4 + r;
        float v = ao[df][r] / l_r[r];
        attn[((size_t)b * 2048 + q) * 2048 + h * 128 + df * 16 + lrow] = f2bf(v);
      }
    bar();
  }
}

// ---------------- modc ----------------
__global__ __launch_bounds__(256) void modc(const unsigned short* __restrict__ attnO,
                                            const unsigned short* __restrict__ h,
                                            const float* __restrict__ A,
                                            float* __restrict__ cvec) {
  const int D = 2048;
  int t = blockIdx.x * 4 + (threadIdx.x >> 6);
  int lane = threadIdx.x & 63;
  float aA[16] = {}, aH[16] = {};
  for (int i = 0; i < D / 64; ++i) {
    int d = i * 64 + lane;
    float av = bf2f(attnO[(size_t)t * D + d]);
    float hv = bf2f(h[(size_t)t * D + d]);
    const float* ar = A + (size_t)d * 16;
#pragma unroll
    for (int j = 0; j < 16; ++j) {
      float a = ar[j];
      aA[j] += av * a;
      aH[j] += hv * a;
    }
  }
#pragma unroll
  for (int j = 0; j < 16; ++j) {
#pragma unroll
    for (int off = 32; off; off >>= 1) {
      aA[j] += __shfl_xor(aA[j], off);
      aH[j] += __shfl_xor(aH[j], off);
    }
  }
#pragma unroll
  for (int j = 0; j < 16; ++j)
    if (lane == j) cvec[(size_t)t * 16 + j] = 0.1f * tanhf(aA[j]) * aH[j];
}

extern "C" void kernel_launch(void* const* d_in, const int* in_sizes, int n_in,
                              void* d_out, int out_size, void* d_ws, size_t ws_size,
                              hipStream_t stream) {
  const float* hs  = (const float*)d_in[0];
  const float* ln1 = (const float*)d_in[1];
  const float* ln2 = (const float*)d_in[2];
  const float* Wq  = (const float*)d_in[3];
  const float* Wk  = (const float*)d_in[4];
  const float* Wv  = (const float*)d_in[5];
  const float* Wo  = (const float*)d_in[6];
  const float* Am  = (const float*)d_in[7];
  const float* Bm  = (const float*)d_in[8];
  const float* Win = (const float*)d_in[9];
  const float* Wup = (const float*)d_in[10];
  const float* Wdn = (const float*)d_in[11];
  float* out = (float*)d_out;
  (void)in_sizes; (void)n_in;

  const int T = 4096;
  const int Dm = 2048, F = 8192;
  const size_t MB = (size_t)1 << 20;

  const size_t need = 184 * MB;
  if (ws_size < need) {
    hipMemsetAsync(d_out, 0, (size_t)out_size * 4, stream);
    return;
  }
  char* base = (char*)d_ws;
  unsigned short* tb    = (unsigned short*)(base);
  unsigned short* wqkv  = (unsigned short*)(base);
  unsigned short* vT    = (unsigned short*)(base);
  unsigned short* xb    = (unsigned short*)(base + 24 * MB);
  unsigned short* attnO = (unsigned short*)(base + 40 * MB);
  unsigned short* qkv   = (unsigned short*)(base + 64 * MB);
  unsigned short* win   = (unsigned short*)(base + 64 * MB);
  unsigned short* wo    = (unsigned short*)(base + 112 * MB);
  unsigned short* hb    = (unsigned short*)(base + 120 * MB);
  unsigned short* attn  = (unsigned short*)(base + 136 * MB);
  float*          cv    = (float*)(base + 136 * MB);
  unsigned short* wup   = (unsigned short*)(base + 152 * MB);
  unsigned short* wdn   = (unsigned short*)(base + 152 * MB);

  // batched QKV/O weight convert (1 launch instead of 4)
  cvt_qkvo<<<2048, 256, 0, stream>>>(Wq, Wk, Wv, Wo, wqkv, wo);
  rmsnorm_dual<<<T, 256, 0, stream>>>(hs, ln1, ln2, xb, hb);

  // QKV projection: 16 x 48 = 768 blocks (3 exact rounds)
  gemm_n128<E_NONE><<<(T / 256) * (3 * Dm / 128), 512, 0, stream>>>(
      xb, wqkv, 3 * Dm, Dm, Dm / 64, qkv, nullptr, nullptr);

  vtrans<<<dim3(32, 2, 32), 256, 0, stream>>>(qkv, vT);
  attn_fwd2<<<dim3(16, 32), 256, 0, stream>>>(qkv, vT, attn);

  // O projection: 16 x 16 = 256 blocks (1 exact round)
  gemm_n128<E_NONE><<<(T / 256) * (Dm / 128), 512, 0, stream>>>(
      attn, wo, Dm, Dm, Dm / 64, attnO, nullptr, nullptr);

  modc<<<T / 4, 256, 0, stream>>>(attnO, hb, Am, cv);

  // MLP weight converts (1 launch instead of 2)
  cvt_gu<<<2048, 256, 0, stream>>>(Win, Wup, win, wup);

  // fused gate/up: 16 x 64 = 1024 blocks (4 exact rounds)
  gemm_mlp256<<<(T / 256) * (F / 128), 512, 0, stream>>>(hb, win, wup, cv, Bm, tb);

  cvt_f32_bf16<<<2048, 256, 0, stream>>>(Wdn, wdn, Dm * F / 4);
  // down + residual: 16 x 16 = 256 blocks (1 exact round), K=8192
  gemm_n128<E_RES><<<(T / 256) * (Dm / 128), 512, 0, stream>>>(
      tb, wdn, Dm, F, F / 64, nullptr, out, hs);
}

// Round 14
// 764.589 us; speedup vs baseline: 1.2509x; 1.0041x over previous
//
#include <hip/hip_runtime.h>

#define DI __device__ __forceinline__

typedef short s16x8 __attribute__((ext_vector_type(8)));
typedef float f32x4 __attribute__((ext_vector_type(4)));

typedef __attribute__((address_space(1))) const unsigned int as1_cuint;
typedef __attribute__((address_space(3))) unsigned int as3_uint;

DI unsigned short f2bf(float f) {
  union { float f; unsigned int u; } v; v.f = f;
  unsigned int r = v.u + 0x7fffu + ((v.u >> 16) & 1u);
  return (unsigned short)(r >> 16);
}
DI float bf2f(unsigned short b) {
  union { unsigned int u; float f; } v; v.u = ((unsigned int)b) << 16;
  return v.f;
}

DI void gl_lds16(const void* g, void* l) {
  __builtin_amdgcn_global_load_lds((as1_cuint*)g, (as3_uint*)l, 16, 0, 0);
}

DI void bar() {
  __builtin_amdgcn_sched_barrier(0);
  __builtin_amdgcn_s_barrier();
  __builtin_amdgcn_sched_barrier(0);
}
DI void vm0() { asm volatile("s_waitcnt vmcnt(0)" ::: "memory"); }
DI void sfence() { __builtin_amdgcn_sched_barrier(0); }

#define MFMA __builtin_amdgcn_mfma_f32_16x16x32_bf16

DI ushort4 cvt4f(float4 v) {
  return make_ushort4(f2bf(v.x), f2bf(v.y), f2bf(v.z), f2bf(v.w));
}

// ---------- batched convert: Wq,Wk,Wv -> wqkv (contiguous), Wo -> wo ----------
__global__ __launch_bounds__(256) void cvt_qkvo(const float* __restrict__ Wq,
                                               const float* __restrict__ Wk,
                                               const float* __restrict__ Wv,
                                               const float* __restrict__ Wo,
                                               unsigned short* __restrict__ wqkv,
                                               unsigned short* __restrict__ wo) {
  const int SEG = 1 << 20;  // 1M float4 per matrix
  int stride = gridDim.x * blockDim.x;
  for (int i = blockIdx.x * blockDim.x + threadIdx.x; i < 4 * SEG; i += stride) {
    int seg = i >> 20, within = i & (SEG - 1);
    const float4* src = (const float4*)(seg == 0 ? Wq : seg == 1 ? Wk : seg == 2 ? Wv : Wo);
    float4 v = src[within];
    if (seg < 3) ((ushort4*)wqkv)[i] = cvt4f(v);
    else ((ushort4*)wo)[within] = cvt4f(v);
  }
}

// ---------- batched convert: Win -> win, Wup -> wup ----------
__global__ __launch_bounds__(256) void cvt_gu(const float* __restrict__ Win,
                                              const float* __restrict__ Wup,
                                              unsigned short* __restrict__ win,
                                              unsigned short* __restrict__ wup) {
  const int SEG = 1 << 22;  // 4M float4 per matrix
  int stride = gridDim.x * blockDim.x;
  for (int i = blockIdx.x * blockDim.x + threadIdx.x; i < 2 * SEG; i += stride) {
    int seg = i >> 22, within = i & (SEG - 1);
    float4 v = ((const float4*)(seg ? Wup : Win))[within];
    ((ushort4*)(seg ? wup : win))[within] = cvt4f(v);
  }
}

// ---------------- fp32 -> bf16 convert (single matrix) ----------------
__global__ __launch_bounds__(256) void cvt_f32_bf16(const float* __restrict__ src,
                                                    unsigned short* __restrict__ dst, int n4) {
  int i = blockIdx.x * blockDim.x + threadIdx.x;
  int stride = gridDim.x * blockDim.x;
  for (; i < n4; i += stride) ((ushort4*)dst)[i] = cvt4f(((const float4*)src)[i]);
}

// ---------------- dual RMSNorm ----------------
__global__ __launch_bounds__(256) void rmsnorm_dual(const float* __restrict__ hs,
                                                    const float* __restrict__ w1,
                                                    const float* __restrict__ w2,
                                                    unsigned short* __restrict__ xo,
                                                    unsigned short* __restrict__ ho) {
  const int D = 2048;
  int t = blockIdx.x, tid = threadIdx.x;
  const float* row = hs + (size_t)t * D;
  float4 a = ((const float4*)row)[tid * 2];
  float4 b = ((const float4*)row)[tid * 2 + 1];
  float ss = a.x * a.x + a.y * a.y + a.z * a.z + a.w * a.w +
             b.x * b.x + b.y * b.y + b.z * b.z + b.w * b.w;
#pragma unroll
  for (int off = 32; off; off >>= 1) ss += __shfl_xor(ss, off);
  __shared__ float red[4];
  int wave = tid >> 6, lane = tid & 63;
  if (lane == 0) red[wave] = ss;
  __syncthreads();
  float tot = red[0] + red[1] + red[2] + red[3];
  float inv = rsqrtf(tot / (float)D + 1e-6f);
  int base = tid * 8;
  float vals[8] = {a.x, a.y, a.z, a.w, b.x, b.y, b.z, b.w};
  float4 w1a = ((const float4*)(w1 + base))[0];
  float4 w1b = ((const float4*)(w1 + base))[1];
  float4 w2a = ((const float4*)(w2 + base))[0];
  float4 w2b = ((const float4*)(w2 + base))[1];
  float w1v[8] = {w1a.x, w1a.y, w1a.z, w1a.w, w1b.x, w1b.y, w1b.z, w1b.w};
  float w2v[8] = {w2a.x, w2a.y, w2a.z, w2a.w, w2b.x, w2b.y, w2b.z, w2b.w};
  unsigned short ox[8], oh[8];
#pragma unroll
  for (int j = 0; j < 8; ++j) {
    float n = vals[j] * inv;
    ox[j] = f2bf(n * w1v[j]);
    oh[j] = f2bf(n * w2v[j]);
  }
  ushort4* xp = (ushort4*)(xo + (size_t)t * D + base);
  ushort4* hp = (ushort4*)(ho + (size_t)t * D + base);
  xp[0] = make_ushort4(ox[0], ox[1], ox[2], ox[3]);
  xp[1] = make_ushort4(ox[4], ox[5], ox[6], ox[7]);
  hp[0] = make_ushort4(oh[0], oh[1], oh[2], oh[3]);
  hp[1] = make_ushort4(oh[4], oh[5], oh[6], oh[7]);
}

// ======== 256x128 1-barrier/K-tile GEMM (double-buffered prefetch) ========
#define E_NONE 0
#define E_RES 3

template <int EPI>
__global__ __launch_bounds__(512, 2) void gemm_n128(
    const unsigned short* __restrict__ Amat, const unsigned short* __restrict__ Bt,
    int N, int K, int NT,
    unsigned short* __restrict__ Cbf, float* __restrict__ Cf,
    const float* __restrict__ Res) {
  __shared__ __align__(16) unsigned short lds[49152];
  int tid = threadIdx.x, lane = tid & 63;
  int w = tid >> 6, wm = w >> 2, wn = w & 3;
  int lr = lane & 15, g = lane >> 4;
  int nbn = N >> 7, nwg = gridDim.x, wg = blockIdx.x;
  int cpx = nwg >> 3;
  int swz = (wg & 7) * cpx + (wg >> 3);
  int tm = swz / nbn, tn = swz - tm * nbn;
  size_t m0 = (size_t)tm * 256, n0 = (size_t)tn * 128;

  int boffA[4][2], boffB[2][2];
#pragma unroll
  for (int mi = 0; mi < 4; ++mi)
#pragma unroll
    for (int kh = 0; kh < 2; ++kh) {
      int row = mi * 32 + wm * 16 + lr;
      boffA[mi][kh] = row * 128 + ((kh * 64 + g * 16) ^ ((row & 7) << 4));
    }
#pragma unroll
  for (int ni = 0; ni < 2; ++ni)
#pragma unroll
    for (int kh = 0; kh < 2; ++kh) {
      int row = ni * 64 + wn * 16 + lr;
      boffB[ni][kh] = row * 128 + ((kh * 64 + g * 16) ^ ((row & 7) << 4));
    }
  const char* ldsb = (const char*)lds;

  int srow = tid >> 3;
  int scb = ((tid & 7) * 16) ^ ((srow & 7) << 4);
  const unsigned short* pA0 = Amat + (m0 + srow) * (size_t)K + (scb >> 1);
  const unsigned short* pA1 = pA0 + (size_t)128 * K;
  const unsigned short* pB  = Bt + (n0 + srow) * (size_t)K + (scb >> 1);
  const size_t jst = (size_t)64 * K;
  int dst = w * 512;

  f32x4 acc[8][2] = {};

  auto stg = [&](const unsigned short* p, int BUF, int SLOT) {
    gl_lds16(p, &lds[BUF * 24576 + SLOT * 8192 + dst]);
    gl_lds16(p + jst, &lds[BUF * 24576 + SLOT * 8192 + 4096 + dst]);
  };
  auto stg_all = [&](int BUF) {
    stg(pA0, BUF, 0); stg(pA1, BUF, 1); stg(pB, BUF, 2);
    pA0 += 64; pA1 += 64; pB += 64;
  };

  stg_all(0);
  vm0();
  bar();

  for (int t = 0; t < NT; ++t) {
    int BUF = t & 1;
    s16x8 afr[4][2], bfr[2][2];
#pragma unroll
    for (int mi = 0; mi < 4; ++mi)
#pragma unroll
      for (int kh = 0; kh < 2; ++kh)
        afr[mi][kh] = *(const s16x8*)(ldsb + BUF * 49152 + 0 * 16384 + boffA[mi][kh]);
#pragma unroll
    for (int ni = 0; ni < 2; ++ni)
#pragma unroll
      for (int kh = 0; kh < 2; ++kh)
        bfr[ni][kh] = *(const s16x8*)(ldsb + BUF * 49152 + 2 * 16384 + boffB[ni][kh]);
    if (t + 1 < NT) stg_all(BUF ^ 1);
    sfence();
    __builtin_amdgcn_s_setprio(1);
#pragma unroll
    for (int mi = 0; mi < 4; ++mi)
#pragma unroll
      for (int ni = 0; ni < 2; ++ni)
#pragma unroll
        for (int kh = 0; kh < 2; ++kh)
          acc[mi][ni] = MFMA(afr[mi][kh], bfr[ni][kh], acc[mi][ni], 0, 0, 0);
    __builtin_amdgcn_s_setprio(0);
    s16x8 af1[4][2];
#pragma unroll
    for (int mi = 0; mi < 4; ++mi)
#pragma unroll
      for (int kh = 0; kh < 2; ++kh)
        af1[mi][kh] = *(const s16x8*)(ldsb + BUF * 49152 + 1 * 16384 + boffA[mi][kh]);
    __builtin_amdgcn_s_setprio(1);
#pragma unroll
    for (int mi = 0; mi < 4; ++mi)
#pragma unroll
      for (int ni = 0; ni < 2; ++ni)
#pragma unroll
        for (int kh = 0; kh < 2; ++kh)
          acc[4 + mi][ni] = MFMA(af1[mi][kh], bfr[ni][kh], acc[4 + mi][ni], 0, 0, 0);
    __builtin_amdgcn_s_setprio(0);
    vm0();
    bar();
  }

#pragma unroll
  for (int mh = 0; mh < 2; ++mh)
#pragma unroll
    for (int mi = 0; mi < 4; ++mi)
#pragma unroll
      for (int r = 0; r < 4; ++r) {
        size_t row = m0 + mh * 128 + mi * 32 + wm * 16 + g * 4 + r;
#pragma unroll
        for (int ni = 0; ni < 2; ++ni) {
          size_t col = n0 + ni * 64 + wn * 16 + lr;
          float v = acc[mh * 4 + mi][ni][r];
          if constexpr (EPI == E_RES) Cf[row * N + col] = Res[row * N + col] + v;
          else Cbf[row * N + col] = f2bf(v);
        }
      }
}

// ===== 256x128 1-barrier/K-tile fused MLP (double-buffered prefetch) =====
__global__ __launch_bounds__(512, 2) void gemm_mlp256(
    const unsigned short* __restrict__ Hm, const unsigned short* __restrict__ Wg,
    const unsigned short* __restrict__ Wu,
    const float* __restrict__ cvec, const float* __restrict__ Bsm,
    unsigned short* __restrict__ Out) {
  const int N = 8192, K = 2048, NT = 32;
  __shared__ __align__(16) unsigned short lds[65536];
  int tid = threadIdx.x, lane = tid & 63;
  int w = tid >> 6, wm = w >> 2, wn = w & 3;
  int lr = lane & 15, g = lane >> 4;
  int nbn = N >> 7, nwg = gridDim.x, wg = blockIdx.x;
  int cpx = nwg >> 3;
  int swz = (wg & 7) * cpx + (wg >> 3);
  int tm = swz / nbn, tn = swz - tm * nbn;
  size_t m0 = (size_t)tm * 256, n0 = (size_t)tn * 128;

  int boffA[4][2], boffB[2][2];
#pragma unroll
  for (int mi = 0; mi < 4; ++mi)
#pragma unroll
    for (int kh = 0; kh < 2; ++kh) {
      int row = mi * 32 + wm * 16 + lr;
      boffA[mi][kh] = row * 128 + ((kh * 64 + g * 16) ^ ((row & 7) << 4));
    }
#pragma unroll
  for (int ni = 0; ni < 2; ++ni)
#pragma unroll
    for (int kh = 0; kh < 2; ++kh) {
      int row = ni * 64 + wn * 16 + lr;
      boffB[ni][kh] = row * 128 + ((kh * 64 + g * 16) ^ ((row & 7) << 4));
    }
  const char* ldsb = (const char*)lds;

  int srow = tid >> 3;
  int scb = ((tid & 7) * 16) ^ ((srow & 7) << 4);
  const unsigned short* pA0 = Hm + (m0 + srow) * (size_t)K + (scb >> 1);
  const unsigned short* pA1 = pA0 + (size_t)128 * K;
  const unsigned short* pBg = Wg + (n0 + srow) * (size_t)K + (scb >> 1);
  const unsigned short* pBu = Wu + (n0 + srow) * (size_t)K + (scb >> 1);
  const size_t jst = (size_t)64 * K;
  int dst = w * 512;

  f32x4 ag[8][2] = {}, au[8][2] = {};

  auto stg = [&](const unsigned short* p, int BUF, int SLOT) {
    gl_lds16(p, &lds[BUF * 32768 + SLOT * 8192 + dst]);
    gl_lds16(p + jst, &lds[BUF * 32768 + SLOT * 8192 + 4096 + dst]);
  };
  auto stg_all = [&](int BUF) {
    stg(pA0, BUF, 0); stg(pA1, BUF, 1); stg(pBg, BUF, 2); stg(pBu, BUF, 3);
    pA0 += 64; pA1 += 64; pBg += 64; pBu += 64;
  };

  stg_all(0);
  vm0();
  bar();

  for (int t = 0; t < NT; ++t) {
    int BUF = t & 1;
    s16x8 afr[4][2], bg[2][2], bu[2][2];
#pragma unroll
    for (int mi = 0; mi < 4; ++mi)
#pragma unroll
      for (int kh = 0; kh < 2; ++kh)
        afr[mi][kh] = *(const s16x8*)(ldsb + BUF * 65536 + 0 * 16384 + boffA[mi][kh]);
#pragma unroll
    for (int ni = 0; ni < 2; ++ni)
#pragma unroll
      for (int kh = 0; kh < 2; ++kh) {
        bg[ni][kh] = *(const s16x8*)(ldsb + BUF * 65536 + 2 * 16384 + boffB[ni][kh]);
        bu[ni][kh] = *(const s16x8*)(ldsb + BUF * 65536 + 3 * 16384 + boffB[ni][kh]);
      }
    if (t + 1 < NT) stg_all(BUF ^ 1);
    sfence();
    __builtin_amdgcn_s_setprio(1);
#pragma unroll
    for (int mi = 0; mi < 4; ++mi)
#pragma unroll
      for (int ni = 0; ni < 2; ++ni)
#pragma unroll
        for (int kh = 0; kh < 2; ++kh) {
          ag[mi][ni] = MFMA(afr[mi][kh], bg[ni][kh], ag[mi][ni], 0, 0, 0);
          au[mi][ni] = MFMA(afr[mi][kh], bu[ni][kh], au[mi][ni], 0, 0, 0);
        }
    __builtin_amdgcn_s_setprio(0);
    s16x8 af1[4][2];
#pragma unroll
    for (int mi = 0; mi < 4; ++mi)
#pragma unroll
      for (int kh = 0; kh < 2; ++kh)
        af1[mi][kh] = *(const s16x8*)(ldsb + BUF * 65536 + 1 * 16384 + boffA[mi][kh]);
    __builtin_amdgcn_s_setprio(1);
#pragma unroll
    for (int mi = 0; mi < 4; ++mi)
#pragma unroll
      for (int ni = 0; ni < 2; ++ni)
#pragma unroll
        for (int kh = 0; kh < 2; ++kh) {
          ag[4 + mi][ni] = MFMA(af1[mi][kh], bg[ni][kh], ag[4 + mi][ni], 0, 0, 0);
          au[4 + mi][ni] = MFMA(af1[mi][kh], bu[ni][kh], au[4 + mi][ni], 0, 0, 0);
        }
    __builtin_amdgcn_s_setprio(0);
    vm0();
    bar();
  }

  // epilogue: c-tile 256x16 f32 + Bsm-tile 16x128 f32 into reused LDS
  float* cl = (float*)lds;          // [256][16]
  float* bl = (float*)&lds[32768];  // [16][128]
#pragma unroll
  for (int j = 0; j < 2; ++j) {
    int fi = tid * 2 + j;
    ((float4*)cl)[fi] = ((const float4*)(cvec + m0 * 16))[fi];
  }
  {
    int fi = tid;
    ((float4*)bl)[fi] = *(const float4*)(Bsm + (size_t)(fi >> 5) * N + n0 + (fi & 31) * 4);
  }
  bar();

#pragma unroll
  for (int mh = 0; mh < 2; ++mh)
#pragma unroll
    for (int mi = 0; mi < 4; ++mi)
#pragma unroll
      for (int r = 0; r < 4; ++r) {
        int rr = mh * 128 + mi * 32 + wm * 16 + g * 4 + r;
        size_t row = m0 + rr;
#pragma unroll
        for (int ni = 0; ni < 2; ++ni) {
          int cc = ni * 64 + wn * 16 + lr;
          size_t col = n0 + cc;
          float s = 0.f;
#pragma unroll
          for (int jj = 0; jj < 16; ++jj) s += cl[rr * 16 + jj] * bl[jj * 128 + cc];
          float gg = ag[mh * 4 + mi][ni][r] + s;
          float sig = 1.f / (1.f + __expf(-gg));
          Out[row * N + col] = f2bf(gg * sig * au[mh * 4 + mi][ni][r]);
        }
      }
}

// ---------- V transpose: vT[bh][d][k] ----------
__global__ __launch_bounds__(256) void vtrans(const unsigned short* __restrict__ qkv,
                                              unsigned short* __restrict__ vT) {
  __shared__ unsigned short t[64][72];
  int bh = blockIdx.z, b = bh >> 4, h = bh & 15;
  int k0 = blockIdx.x * 64, d0 = blockIdx.y * 64;
  int tid = threadIdx.x;
#pragma unroll
  for (int j = 0; j < 2; ++j) {
    int idx = tid + j * 256;
    int r = idx >> 3, c8 = (idx & 7) * 8;
    s16x8 v = *(const s16x8*)(qkv + ((size_t)(b * 2048 + k0 + r)) * 6144 + 4096 + h * 128 + d0 + c8);
#pragma unroll
    for (int e = 0; e < 8; ++e) t[r][c8 + e] = (unsigned short)v[e];
  }
  __syncthreads();
#pragma unroll
  for (int j = 0; j < 2; ++j) {
    int idx = tid + j * 256;
    int dr = idx >> 3, k8 = (idx & 7) * 8;
    s16x8 o;
#pragma unroll
    for (int e = 0; e < 8; ++e) o[e] = (short)t[k8 + e][dr];
    *(s16x8*)(vT + (size_t)bh * 262144 + (size_t)(d0 + dr) * 2048 + k0 + k8) = o;
  }
}

// ---------- causal flash attention v3: KVBLK=64, double-staged k-tile pairs ----------
// LDS 72KB (2 blocks/CU): Kt[2][8192], Vt[2][8192], Pl[4096].
// Per 2 k-tiles: one {bar, stage both, vm0, bar} then two compute rounds back-to-back.
__global__ __launch_bounds__(256, 2) void attn_fwd3(const unsigned short* __restrict__ qkv,
                                                    const unsigned short* __restrict__ vT,
                                                    unsigned short* __restrict__ attn) {
  const int LD = 6144;
  __shared__ __align__(16) unsigned short Kt[16384];
  __shared__ __align__(16) unsigned short Vt[16384];
  __shared__ __align__(16) unsigned short Pl[4096];
  int tid = threadIdx.x, w = tid >> 6, lane = tid & 63;
  int lrow = lane & 15, g = lane >> 4;
  int qp = blockIdx.x, bh = blockIdx.y, b = bh >> 4, h = bh & 15;
  const unsigned short* Qb = qkv + (size_t)b * 2048 * LD + h * 128;
  const unsigned short* Kb = Qb + 2048;
  const unsigned short* vTb = vT + (size_t)bh * 262144;
  const float scale = 0.08838834764831845f;

#pragma unroll
  for (int pass = 0; pass < 2; ++pass) {
    int qtile = pass ? (31 - qp) : qp;
    int wq0 = qtile * 64 + w * 16;
    s16x8 qf[4];
#pragma unroll
    for (int kc = 0; kc < 4; ++kc)
      qf[kc] = *(const s16x8*)(Qb + (size_t)(wq0 + lrow) * LD + kc * 32 + g * 8);
    f32x4 ao[8] = {};
    float m_r[4], l_r[4];
#pragma unroll
    for (int r = 0; r < 4; ++r) { m_r[r] = -1e30f; l_r[r] = 0.f; }
    int nkt = qtile + 1;

    for (int kt = 0; kt < nkt; kt += 2) {
      bar();
#pragma unroll
      for (int bu = 0; bu < 2; ++bu) {
        int ktt = kt + bu;
        if (ktt >= nkt) break;
        int k0 = ktt * 64;
#pragma unroll
        for (int j = 0; j < 4; ++j) {
          int o = j * 4096 + tid * 16;
          int row = o >> 8, cb = o & 255;
          int scb = cb ^ ((row & 7) << 4);
          gl_lds16(Kb + (size_t)(k0 + row) * LD + (scb >> 1),
                   &Kt[bu * 8192 + ((j * 4096 + w * 1024) >> 1)]);
        }
#pragma unroll
        for (int j = 0; j < 4; ++j) {
          int o = j * 4096 + tid * 16;
          int row = o >> 7, cb = o & 127;
          int scb = cb ^ ((row & 7) << 4);
          gl_lds16(vTb + (size_t)row * 2048 + k0 + (scb >> 1),
                   &Vt[bu * 8192 + ((j * 4096 + w * 1024) >> 1)]);
        }
      }
      vm0();
      bar();
#pragma unroll
      for (int bu = 0; bu < 2; ++bu) {
        int ktt = kt + bu;
        if (ktt >= nkt) break;
        int k0 = ktt * 64;
        int kb = bu * 8192;
        f32x4 sa[4] = {};
#pragma unroll
        for (int ni = 0; ni < 4; ++ni)
#pragma unroll
          for (int kc = 0; kc < 4; ++kc) {
            int row = ni * 16 + lrow;
            int cb = kc * 64 + g * 16;
            int scb = cb ^ ((row & 7) << 4);
            s16x8 kf = *(const s16x8*)&Kt[kb + row * 128 + (scb >> 1)];
            sa[ni] = MFMA(qf[kc], kf, sa[ni], 0, 0, 0);
          }
        if (k0 + 63 > wq0) {
#pragma unroll
          for (int ni = 0; ni < 4; ++ni)
#pragma unroll
            for (int r = 0; r < 4; ++r) {
              int q_idx = wq0 + g * 4 + r, k_idx = k0 + ni * 16 + lrow;
              float sv = sa[ni][r] * scale;
              sa[ni][r] = (k_idx > q_idx) ? -1e30f : sv;
            }
        } else {
#pragma unroll
          for (int ni = 0; ni < 4; ++ni)
#pragma unroll
            for (int r = 0; r < 4; ++r) sa[ni][r] *= scale;
        }
        float mt[4];
#pragma unroll
        for (int r = 0; r < 4; ++r)
          mt[r] = fmaxf(fmaxf(sa[0][r], sa[1][r]), fmaxf(sa[2][r], sa[3][r]));
#pragma unroll
        for (int r = 0; r < 4; ++r)
#pragma unroll
          for (int off = 8; off; off >>= 1) mt[r] = fmaxf(mt[r], __shfl_xor(mt[r], off));
        float al[4];
#pragma unroll
        for (int r = 0; r < 4; ++r) {
          float mn = fmaxf(m_r[r], mt[r]);
          al[r] = __expf(m_r[r] - mn);
          m_r[r] = mn;
        }
        float rs[4] = {0.f, 0.f, 0.f, 0.f};
#pragma unroll
        for (int ni = 0; ni < 4; ++ni)
#pragma unroll
          for (int r = 0; r < 4; ++r) {
            float p = __expf(sa[ni][r] - m_r[r]);
            rs[r] += p;
            int q = g * 4 + r, k = ni * 16 + lrow;
            Pl[w * 1024 + q * 64 + (k ^ ((q & 7) << 3))] = f2bf(p);
          }
#pragma unroll
        for (int r = 0; r < 4; ++r) {
#pragma unroll
          for (int off = 8; off; off >>= 1) rs[r] += __shfl_xor(rs[r], off);
          l_r[r] = l_r[r] * al[r] + rs[r];
        }
#pragma unroll
        for (int df = 0; df < 8; ++df)
#pragma unroll
          for (int r = 0; r < 4; ++r) ao[df][r] *= al[r];
        asm volatile("s_waitcnt lgkmcnt(0)" ::: "memory");
        __builtin_amdgcn_sched_barrier(0);
        s16x8 pa[2];
#pragma unroll
        for (int ks = 0; ks < 2; ++ks)
          pa[ks] = *(const s16x8*)&Pl[w * 1024 + lrow * 64 + ((ks * 32 + g * 8) ^ ((lrow & 7) << 3))];
#pragma unroll
        for (int df = 0; df < 8; ++df) {
#pragma unroll
          for (int ks = 0; ks < 2; ++ks) {
            int row = df * 16 + lrow;
            int cb = ks * 64 + g * 16;
            int scb = cb ^ ((row & 7) << 4);
            s16x8 vf = *(const s16x8*)&Vt[kb + row * 64 + (scb >> 1)];
            ao[df] = MFMA(pa[ks], vf, ao[df], 0, 0, 0);
          }
        }
      }
    }
#pragma unroll
    for (int df = 0; df < 8; ++df)
#pragma unroll
      for (int r = 0; r < 4; ++r) {
        int q = wq0 + g * 4 + r;
        float v = ao[df][r] / l_r[r];
        attn[((size_t)b * 2048 + q) * 2048 + h * 128 + df * 16 + lrow] = f2bf(v);
      }
    bar();
  }
}

// ---------------- modc ----------------
__global__ __launch_bounds__(256) void modc(const unsigned short* __restrict__ attnO,
                                            const unsigned short* __restrict__ h,
                                            const float* __restrict__ A,
                                            float* __restrict__ cvec) {
  const int D = 2048;
  int t = blockIdx.x * 4 + (threadIdx.x >> 6);
  int lane = threadIdx.x & 63;
  float aA[16] = {}, aH[16] = {};
  for (int i = 0; i < D / 64; ++i) {
    int d = i * 64 + lane;
    float av = bf2f(attnO[(size_t)t * D + d]);
    float hv = bf2f(h[(size_t)t * D + d]);
    const float* ar = A + (size_t)d * 16;
#pragma unroll
    for (int j = 0; j < 16; ++j) {
      float a = ar[j];
      aA[j] += av * a;
      aH[j] += hv * a;
    }
  }
#pragma unroll
  for (int j = 0; j < 16; ++j) {
#pragma unroll
    for (int off = 32; off; off >>= 1) {
      aA[j] += __shfl_xor(aA[j], off);
      aH[j] += __shfl_xor(aH[j], off);
    }
  }
#pragma unroll
  for (int j = 0; j < 16; ++j)
    if (lane == j) cvec[(size_t)t * 16 + j] = 0.1f * tanhf(aA[j]) * aH[j];
}

extern "C" void kernel_launch(void* const* d_in, const int* in_sizes, int n_in,
                              void* d_out, int out_size, void* d_ws, size_t ws_size,
                              hipStream_t stream) {
  const float* hs  = (const float*)d_in[0];
  const float* ln1 = (const float*)d_in[1];
  const float* ln2 = (const float*)d_in[2];
  const float* Wq  = (const float*)d_in[3];
  const float* Wk  = (const float*)d_in[4];
  const float* Wv  = (const float*)d_in[5];
  const float* Wo  = (const float*)d_in[6];
  const float* Am  = (const float*)d_in[7];
  const float* Bm  = (const float*)d_in[8];
  const float* Win = (const float*)d_in[9];
  const float* Wup = (const float*)d_in[10];
  const float* Wdn = (const float*)d_in[11];
  float* out = (float*)d_out;
  (void)in_sizes; (void)n_in;

  const int T = 4096;
  const int Dm = 2048, F = 8192;
  const size_t MB = (size_t)1 << 20;

  const size_t need = 184 * MB;
  if (ws_size < need) {
    hipMemsetAsync(d_out, 0, (size_t)out_size * 4, stream);
    return;
  }
  char* base = (char*)d_ws;
  unsigned short* tb    = (unsigned short*)(base);
  unsigned short* wqkv  = (unsigned short*)(base);
  unsigned short* vT    = (unsigned short*)(base);
  unsigned short* xb    = (unsigned short*)(base + 24 * MB);
  unsigned short* attnO = (unsigned short*)(base + 40 * MB);
  unsigned short* qkv   = (unsigned short*)(base + 64 * MB);
  unsigned short* win   = (unsigned short*)(base + 64 * MB);
  unsigned short* wo    = (unsigned short*)(base + 112 * MB);
  unsigned short* hb    = (unsigned short*)(base + 120 * MB);
  unsigned short* attn  = (unsigned short*)(base + 136 * MB);
  float*          cv    = (float*)(base + 136 * MB);
  unsigned short* wup   = (unsigned short*)(base + 152 * MB);
  unsigned short* wdn   = (unsigned short*)(base + 152 * MB);

  cvt_qkvo<<<2048, 256, 0, stream>>>(Wq, Wk, Wv, Wo, wqkv, wo);
  rmsnorm_dual<<<T, 256, 0, stream>>>(hs, ln1, ln2, xb, hb);

  // QKV projection: 16 x 48 = 768 blocks (3 exact rounds)
  gemm_n128<E_NONE><<<(T / 256) * (3 * Dm / 128), 512, 0, stream>>>(
      xb, wqkv, 3 * Dm, Dm, Dm / 64, qkv, nullptr, nullptr);

  vtrans<<<dim3(32, 2, 32), 256, 0, stream>>>(qkv, vT);
  attn_fwd3<<<dim3(16, 32), 256, 0, stream>>>(qkv, vT, attn);

  // O projection: 16 x 16 = 256 blocks (1 exact round)
  gemm_n128<E_NONE><<<(T / 256) * (Dm / 128), 512, 0, stream>>>(
      attn, wo, Dm, Dm, Dm / 64, attnO, nullptr, nullptr);

  modc<<<T / 4, 256, 0, stream>>>(attnO, hb, Am, cv);

  cvt_gu<<<2048, 256, 0, stream>>>(Win, Wup, win, wup);

  // fused gate/up: 16 x 64 = 1024 blocks (4 exact rounds)
  gemm_mlp256<<<(T / 256) * (F / 128), 512, 0, stream>>>(hb, win, wup, cv, Bm, tb);

  cvt_f32_bf16<<<2048, 256, 0, stream>>>(Wdn, wdn, Dm * F / 4);
  // down + residual: 16 x 16 = 256 blocks (1 exact round), K=8192
  gemm_n128<E_RES><<<(T / 256) * (Dm / 128), 512, 0, stream>>>(
      tb, wdn, Dm, F, F / 64, nullptr, out, hs);
}